// Round 6
// baseline (107.489 us; speedup 1.0000x reference)
//
#include <hip/hip_runtime.h>

typedef __bf16 bf16x8 __attribute__((ext_vector_type(8)));
typedef float f32x4 __attribute__((ext_vector_type(4)));
typedef unsigned short u16x8 __attribute__((ext_vector_type(8)));
typedef unsigned short u16x4 __attribute__((ext_vector_type(4)));

#define B_ 32
#define CC 512
#define HW 192
#define C8_ 64
#define NTRI 528
#define TILE_B 24576      // one 192x64 bf16 tile, 128B rows
#define SMEM_BYTES 102912

__device__ inline unsigned short f2bf(float f) {
    unsigned u = __float_as_uint(f);
    unsigned r = (u + 0x7FFFu + ((u >> 16) & 1u)) >> 16;
    return (unsigned short)r;
}

__device__ inline void gload16(const void* g, void* l) {
    __builtin_amdgcn_global_load_lds(
        (const __attribute__((address_space(1))) unsigned*)g,
        (__attribute__((address_space(3))) unsigned*)l,
        16, 0, 0);
}

// ---------------- Kernel 1: x [B][C][HW] f32 -> xt [B][HW][C] bf16 ----------
__global__ void k_transpose(const float* __restrict__ x,
                            unsigned short* __restrict__ xt) {
    __shared__ unsigned short tile[64 * 64];
    int b = blockIdx.x / 3, mt = blockIdx.x % 3;
    int m0 = mt * 64, c0 = blockIdx.y * 64;
    int t = threadIdx.x;
    const float* xb = x + (size_t)b * CC * HW + (size_t)c0 * HW + m0;

    int mq = t & 15, cl0 = t >> 4;
    int sw = (mq & 7) << 3;
    #pragma unroll
    for (int rd = 0; rd < 4; ++rd) {
        int cl = rd * 16 + cl0;
        f32x4 v = *(const f32x4*)(xb + cl * HW + mq * 4);
        #pragma unroll
        for (int e = 0; e < 4; ++e)
            tile[(mq * 4 + e) * 64 + (cl ^ sw)] = f2bf(v[e]);
    }
    __syncthreads();
    unsigned short* xo = xt + ((size_t)b * HW + m0) * CC + c0;
    int kc = t & 7, mr0 = t >> 3;
    #pragma unroll
    for (int rd = 0; rd < 2; ++rd) {
        int mr = rd * 32 + mr0;
        u16x8 v = *(const u16x8*)&tile[mr * 64 + ((kc << 3) ^ (((mr >> 2) & 7) << 3))];
        *(u16x8*)(xo + (size_t)mr * CC + kc * 8) = v;
    }
}

// ---------------- Kernel 2: precast Wq/Wk -> bf16 ---------------------------
__global__ void wcvt(const float* __restrict__ Wq, const float* __restrict__ Wk,
                     unsigned short* __restrict__ wqb, unsigned short* __restrict__ wkb) {
    const float* src = (blockIdx.x < 32) ? Wq : Wk;
    unsigned short* dst = (blockIdx.x < 32) ? wqb : wkb;
    int base = (blockIdx.x & 31) * 1024 + threadIdx.x * 4;
    f32x4 a = *(const f32x4*)(src + base);
    u16x4 o;
    #pragma unroll
    for (int e = 0; e < 4; ++e) o[e] = f2bf(a[e]);
    *(u16x4*)(dst + base) = o;
}

// ---------------- Kernel 3: PAM standalone (32 blocks x 512 thr) ------------
__global__ __launch_bounds__(512) void pam(
        const unsigned short* __restrict__ xt,
        const unsigned short* __restrict__ wqb, const unsigned short* __restrict__ wkb,
        const float* __restrict__ bq, const float* __restrict__ bk,
        float* __restrict__ out) {
    __shared__ __attribute__((aligned(16))) unsigned short qs[HW * C8_];
    __shared__ __attribute__((aligned(16))) unsigned short ks[HW * C8_];
    __shared__ float red[8 * 48];
    int b = blockIdx.x;
    int tid = threadIdx.x, w = tid >> 6, lane = tid & 63;
    int l15 = lane & 15, lq = lane >> 4;
    const unsigned short* xb = xt + (size_t)b * HW * CC;

    // phase 1: waves 0-3 compute q (16 qc each), waves 4-7 compute k
    {
        int w4 = w & 3;
        int qc = w4 * 16 + l15;
        bool isq = (w < 4);
        const unsigned short* wp = (isq ? wqb : wkb) + (size_t)qc * CC;
        float bias = isq ? bq[qc] : bk[qc];
        unsigned short* dst = isq ? qs : ks;
        for (int mgrp = 0; mgrp < 4; ++mgrp) {
            int m0 = mgrp * 48;
            f32x4 a3[3];
            #pragma unroll
            for (int i = 0; i < 3; ++i) a3[i] = (f32x4){0.f, 0.f, 0.f, 0.f};
            #pragma unroll 4
            for (int kt = 0; kt < 16; ++kt) {
                int ko8 = kt * 32 + lq * 8;
                bf16x8 wf = *(const bf16x8*)(wp + ko8);
                #pragma unroll
                for (int i = 0; i < 3; ++i) {
                    bf16x8 af = *(const bf16x8*)(xb + (m0 + i * 16 + l15) * CC + ko8);
                    a3[i] = __builtin_amdgcn_mfma_f32_16x16x32_bf16(af, wf, a3[i], 0, 0, 0);
                }
            }
            #pragma unroll
            for (int i = 0; i < 3; ++i) {
                #pragma unroll
                for (int r = 0; r < 4; ++r) {
                    int m = m0 + i * 16 + lq * 4 + r;
                    int pos = m * 64 + ((((qc >> 3) ^ (m & 7)) << 3) | (qc & 7));
                    dst[pos] = f2bf(a3[i][r] + bias);
                }
            }
        }
    }
    __syncthreads();

    // phase 2: energy = q k^T, fused row-max over n
    {
        int mgrp = w >> 1, nh = w & 1;
        int m0 = mgrp * 48, n0 = nh * 96;
        f32x4 acc[3][6];
        #pragma unroll
        for (int i = 0; i < 3; ++i)
            #pragma unroll
            for (int j = 0; j < 6; ++j)
                acc[i][j] = (f32x4){0.f, 0.f, 0.f, 0.f};
        #pragma unroll
        for (int kt2 = 0; kt2 < 2; ++kt2) {
            int chunk = kt2 * 4 + lq;
            bf16x8 af[3], bfr[6];
            #pragma unroll
            for (int i = 0; i < 3; ++i) {
                int m = m0 + i * 16 + l15;
                af[i] = *(const bf16x8*)&qs[m * 64 + ((chunk ^ (m & 7)) << 3)];
            }
            #pragma unroll
            for (int j = 0; j < 6; ++j) {
                int n = n0 + j * 16 + l15;
                bfr[j] = *(const bf16x8*)&ks[n * 64 + ((chunk ^ (n & 7)) << 3)];
            }
            #pragma unroll
            for (int i = 0; i < 3; ++i)
                #pragma unroll
                for (int j = 0; j < 6; ++j)
                    acc[i][j] = __builtin_amdgcn_mfma_f32_16x16x32_bf16(
                        af[i], bfr[j], acc[i][j], 0, 0, 0);
        }
        #pragma unroll
        for (int i = 0; i < 3; ++i) {
            float rm[4];
            #pragma unroll
            for (int r = 0; r < 4; ++r) rm[r] = -1e30f;
            #pragma unroll
            for (int j = 0; j < 6; ++j)
                #pragma unroll
                for (int r = 0; r < 4; ++r)
                    rm[r] = fmaxf(rm[r], acc[i][j][r]);
            #pragma unroll
            for (int msk = 1; msk <= 8; msk <<= 1)
                #pragma unroll
                for (int r = 0; r < 4; ++r)
                    rm[r] = fmaxf(rm[r], __shfl_xor(rm[r], msk));
            if (l15 == 0) {
                #pragma unroll
                for (int r = 0; r < 4; ++r)
                    red[((mgrp << 1) | nh) * 48 + i * 16 + lq * 4 + r] = rm[r];
            }
        }
    }
    __syncthreads();
    if (tid < HW) {
        int mg = tid / 48, mr = tid % 48;
        float v = fmaxf(red[(mg * 2) * 48 + mr], red[(mg * 2 + 1) * 48 + mr]);
        out[((size_t)B_ * B_ + b) * HW + tid] = v;
    }
}

// ---------------- Kernel 4: Gram tiles + fused row/col max (round-3) --------
__global__ __launch_bounds__(512) void gram(const unsigned short* __restrict__ xt,
                                            float* __restrict__ out) {
    extern __shared__ char smem[];
    float* colbuf = (float*)(smem + 2 * TILE_B * 2);           // [2][192]
    float* rowbuf = (float*)(smem + 2 * TILE_B * 2 + 1536);    // [4][192]

    int tid = threadIdx.x;
    int bid = (blockIdx.x & 7) * 66 + (blockIdx.x >> 3);       // 528 = 8*66
    int idx = bid, g = 0;
    while (idx >= B_ - g) { idx -= B_ - g; ++g; }
    int p = g + idx;

    const unsigned short* xg = xt + (size_t)g * HW * CC;
    const unsigned short* xp = xt + (size_t)p * HW * CC;

    int w = tid >> 6, lane = tid & 63;
    int wr = w >> 2, wc = w & 3;                // 2 x 4 wave grid
    int l15 = lane & 15, lq = lane >> 4;

    int l8 = lane >> 3, s8 = lane & 7;
    const unsigned short* agp = xg + (size_t)(24 * w + l8) * CC + ((s8 ^ l8) << 3);
    const unsigned short* bgp = xp + (size_t)(24 * w + l8) * CC + ((s8 ^ l8) << 3);
    unsigned ldsw = (unsigned)(24 * w) * 128;

    unsigned aoff[6], boff[3];
    #pragma unroll
    for (int i = 0; i < 6; ++i) {
        int row = wr * 96 + i * 16 + l15;
        aoff[i] = row * 128 + ((unsigned)(lq ^ (row & 7)) << 4);
    }
    #pragma unroll
    for (int j = 0; j < 3; ++j) {
        int row = wc * 48 + j * 16 + l15;
        boff[j] = row * 128 + ((unsigned)(lq ^ (row & 7)) << 4);
    }

    f32x4 acc[6][3];
    #pragma unroll
    for (int i = 0; i < 6; ++i)
        #pragma unroll
        for (int j = 0; j < 3; ++j)
            acc[i][j] = (f32x4){0.f, 0.f, 0.f, 0.f};

    #define STAGE(buf, k0)                                                     \
        {                                                                      \
            char* ab = smem + (buf) * TILE_B + ldsw;                           \
            char* bb = smem + 2 * TILE_B + (buf) * TILE_B + ldsw;              \
            _Pragma("unroll")                                                  \
            for (int ci = 0; ci < 3; ++ci) {                                   \
                gload16(agp + (k0) + ci * 8 * CC, ab + ci * 1024);             \
                gload16(bgp + (k0) + ci * 8 * CC, bb + ci * 1024);             \
            }                                                                  \
        }

    STAGE(0, 0);
    __syncthreads();

    for (int kt = 0; kt < 8; ++kt) {
        int cur = kt & 1;
        if (kt < 7) STAGE(cur ^ 1, (kt + 1) * 64);
        const char* Ab = smem + cur * TILE_B;
        const char* Bb = smem + 2 * TILE_B + cur * TILE_B;
        #pragma unroll
        for (int kx = 0; kx < 128; kx += 64) {   // kk = 0, 32
            bf16x8 af[6], bfr[3];
            #pragma unroll
            for (int i = 0; i < 6; ++i)
                af[i] = *(const bf16x8*)(Ab + (aoff[i] ^ kx));
            #pragma unroll
            for (int j = 0; j < 3; ++j)
                bfr[j] = *(const bf16x8*)(Bb + (boff[j] ^ kx));
            #pragma unroll
            for (int i = 0; i < 6; ++i)
                #pragma unroll
                for (int j = 0; j < 3; ++j)
                    acc[i][j] = __builtin_amdgcn_mfma_f32_16x16x32_bf16(
                        af[i], bfr[j], acc[i][j], 0, 0, 0);
        }
        __syncthreads();
    }

    #pragma unroll
    for (int j = 0; j < 3; ++j) {
        float cm = -1e30f;
        #pragma unroll
        for (int i = 0; i < 6; ++i)
            #pragma unroll
            for (int r = 0; r < 4; ++r)
                cm = fmaxf(cm, acc[i][j][r]);
        cm = fmaxf(cm, __shfl_xor(cm, 16));
        cm = fmaxf(cm, __shfl_xor(cm, 32));
        if (lane < 16) colbuf[wr * HW + wc * 48 + j * 16 + l15] = cm;
    }
    #pragma unroll
    for (int i = 0; i < 6; ++i) {
        float rm[4];
        #pragma unroll
        for (int r = 0; r < 4; ++r) rm[r] = -1e30f;
        #pragma unroll
        for (int j = 0; j < 3; ++j)
            #pragma unroll
            for (int r = 0; r < 4; ++r)
                rm[r] = fmaxf(rm[r], acc[i][j][r]);
        #pragma unroll
        for (int msk = 1; msk <= 8; msk <<= 1)
            #pragma unroll
            for (int r = 0; r < 4; ++r)
                rm[r] = fmaxf(rm[r], __shfl_xor(rm[r], msk));
        if (l15 == 0) {
            #pragma unroll
            for (int r = 0; r < 4; ++r)
                rowbuf[wc * HW + wr * 96 + i * 16 + lq * 4 + r] = rm[r];
        }
    }
    __syncthreads();
    if (tid < HW) {
        float cmax = fmaxf(colbuf[tid], colbuf[HW + tid]);
        out[((size_t)g * B_ + p) * HW + tid] = cmax;
        float rmax = fmaxf(fmaxf(rowbuf[tid], rowbuf[HW + tid]),
                           fmaxf(rowbuf[2 * HW + tid], rowbuf[3 * HW + tid]));
        out[((size_t)p * B_ + g) * HW + tid] = rmax;
    }
}

extern "C" void kernel_launch(void* const* d_in, const int* in_sizes, int n_in,
                              void* d_out, int out_size, void* d_ws, size_t ws_size,
                              hipStream_t stream) {
    (void)in_sizes; (void)n_in; (void)out_size; (void)ws_size;
    const float* x  = (const float*)d_in[0];
    const float* Wq = (const float*)d_in[1];
    const float* bq = (const float*)d_in[2];
    const float* Wk = (const float*)d_in[3];
    const float* bk = (const float*)d_in[4];
    float* out = (float*)d_out;

    char* ws = (char*)d_ws;
    unsigned short* xt  = (unsigned short*)ws;                  // 6291456 B
    unsigned short* wqb = (unsigned short*)(ws + 6291456);      // 65536 B
    unsigned short* wkb = (unsigned short*)(ws + 6291456 + 65536);

    hipFuncSetAttribute((const void*)gram,
                        hipFuncAttributeMaxDynamicSharedMemorySize, SMEM_BYTES);

    k_transpose<<<dim3(96, 8), dim3(256), 0, stream>>>(x, xt);
    wcvt<<<dim3(64), dim3(256), 0, stream>>>(Wq, Wk, wqb, wkb);
    pam<<<dim3(32), dim3(512), 0, stream>>>(xt, wqb, wkb, bq, bk, out);
    gram<<<dim3(NTRI), dim3(512), SMEM_BYTES, stream>>>(xt, out);
}

// Round 7
// 62.415 us; speedup vs baseline: 1.7222x; 1.7222x over previous
//
#include <hip/hip_runtime.h>

typedef __bf16 bf16x8 __attribute__((ext_vector_type(8)));
typedef float f32x4 __attribute__((ext_vector_type(4)));
typedef unsigned short u16x8 __attribute__((ext_vector_type(8)));
typedef unsigned short u16x4 __attribute__((ext_vector_type(4)));

#define B_ 32
#define CC 512
#define HW 192
#define C8_ 64
#define NTRI 528
#define TILE_B 24576      // one 192x64 bf16 tile, 128B rows
#define SMEM_BYTES 102912

__device__ inline unsigned short f2bf(float f) {
    unsigned u = __float_as_uint(f);
    unsigned r = (u + 0x7FFFu + ((u >> 16) & 1u)) >> 16;
    return (unsigned short)r;
}

__device__ inline void gload16(const void* g, void* l) {
    __builtin_amdgcn_global_load_lds(
        (const __attribute__((address_space(1))) unsigned*)g,
        (__attribute__((address_space(3))) unsigned*)l,
        16, 0, 0);
}

// ---------------- Kernel 1: x [B][C][HW] f32 -> xt [B][HW][C] bf16 ----------
__global__ void k_transpose(const float* __restrict__ x,
                            unsigned short* __restrict__ xt) {
    __shared__ unsigned short tile[64 * 64];
    int b = blockIdx.x / 3, mt = blockIdx.x % 3;
    int m0 = mt * 64, c0 = blockIdx.y * 64;
    int t = threadIdx.x;
    const float* xb = x + (size_t)b * CC * HW + (size_t)c0 * HW + m0;

    int mq = t & 15, cl0 = t >> 4;
    int sw = (mq & 7) << 3;
    #pragma unroll
    for (int rd = 0; rd < 4; ++rd) {
        int cl = rd * 16 + cl0;
        f32x4 v = *(const f32x4*)(xb + cl * HW + mq * 4);
        #pragma unroll
        for (int e = 0; e < 4; ++e)
            tile[(mq * 4 + e) * 64 + (cl ^ sw)] = f2bf(v[e]);
    }
    __syncthreads();
    unsigned short* xo = xt + ((size_t)b * HW + m0) * CC + c0;
    int kc = t & 7, mr0 = t >> 3;
    #pragma unroll
    for (int rd = 0; rd < 2; ++rd) {
        int mr = rd * 32 + mr0;
        u16x8 v = *(const u16x8*)&tile[mr * 64 + ((kc << 3) ^ (((mr >> 2) & 7) << 3))];
        *(u16x8*)(xo + (size_t)mr * CC + kc * 8) = v;
    }
}

// ---------------- Kernel 2: precast Wq/Wk -> bf16 ---------------------------
__global__ void wcvt(const float* __restrict__ Wq, const float* __restrict__ Wk,
                     unsigned short* __restrict__ wqb, unsigned short* __restrict__ wkb) {
    const float* src = (blockIdx.x < 32) ? Wq : Wk;
    unsigned short* dst = (blockIdx.x < 32) ? wqb : wkb;
    int base = (blockIdx.x & 31) * 1024 + threadIdx.x * 4;
    f32x4 a = *(const f32x4*)(src + base);
    u16x4 o;
    #pragma unroll
    for (int e = 0; e < 4; ++e) o[e] = f2bf(a[e]);
    *(u16x4*)(dst + base) = o;
}

// ---------------- Kernel 3: q/k projections via MFMA (round-2 structure) ----
// grid (32, 4), block 256 (4 waves). Block: batch b, 48 m-rows, all 64 qc.
// Wave w owns qc0 = w*16 for BOTH q and k. Precast bf16 weights.
__global__ __launch_bounds__(256) void pam_qk(
        const unsigned short* __restrict__ xt,
        const unsigned short* __restrict__ wqb, const unsigned short* __restrict__ wkb,
        const float* __restrict__ bq, const float* __restrict__ bk,
        unsigned short* __restrict__ qo, unsigned short* __restrict__ ko) {
    int b = blockIdx.x, m0 = blockIdx.y * 48;
    int tid = threadIdx.x, w = tid >> 6, lane = tid & 63;
    int l15 = lane & 15, lq = lane >> 4;
    int qc = w * 16 + l15;

    f32x4 accq[3], acck[3];
    #pragma unroll
    for (int i = 0; i < 3; ++i) {
        accq[i] = (f32x4){0.f, 0.f, 0.f, 0.f};
        acck[i] = (f32x4){0.f, 0.f, 0.f, 0.f};
    }

    const unsigned short* xb = xt + ((size_t)b * HW + m0) * CC;
    const unsigned short* wqp = wqb + (size_t)qc * CC;
    const unsigned short* wkp = wkb + (size_t)qc * CC;

    for (int kt = 0; kt < 16; ++kt) {
        int ko8 = kt * 32 + lq * 8;
        bf16x8 wqf = *(const bf16x8*)(wqp + ko8);
        bf16x8 wkf = *(const bf16x8*)(wkp + ko8);
        bf16x8 af[3];
        #pragma unroll
        for (int i = 0; i < 3; ++i)
            af[i] = *(const bf16x8*)(xb + (i * 16 + l15) * CC + ko8);
        #pragma unroll
        for (int i = 0; i < 3; ++i) {
            accq[i] = __builtin_amdgcn_mfma_f32_16x16x32_bf16(af[i], wqf, accq[i], 0, 0, 0);
            acck[i] = __builtin_amdgcn_mfma_f32_16x16x32_bf16(af[i], wkf, acck[i], 0, 0, 0);
        }
    }

    float bqv = bq[qc], bkv = bk[qc];
    // D layout: col = lane&15 (qc), row = lq*4 + r (m within fragment)
    #pragma unroll
    for (int i = 0; i < 3; ++i) {
        #pragma unroll
        for (int r = 0; r < 4; ++r) {
            int m = m0 + i * 16 + lq * 4 + r;
            qo[((size_t)b * HW + m) * C8_ + qc] = f2bf(accq[i][r] + bqv);
            ko[((size_t)b * HW + m) * C8_ + qc] = f2bf(acck[i][r] + bkv);
        }
    }
}

// ---------------- Kernel 4: energy = q k^T per batch, fused row-max ---------
// grid (32, 4), block 256 (4 waves). Block: batch b, rows m0..m0+47, all 192 n.
__global__ __launch_bounds__(256) void pam_energy(
        const unsigned short* __restrict__ qo,
        const unsigned short* __restrict__ ko,
        float* __restrict__ out) {
    int b = blockIdx.x, m0 = blockIdx.y * 48;
    int tid = threadIdx.x, w = tid >> 6, lane = tid & 63;
    int l15 = lane & 15, lq = lane >> 4;
    int n0 = w * 48;

    f32x4 acc[3][3];
    #pragma unroll
    for (int i = 0; i < 3; ++i)
        #pragma unroll
        for (int j = 0; j < 3; ++j)
            acc[i][j] = (f32x4){0.f, 0.f, 0.f, 0.f};

    const unsigned short* qb = qo + ((size_t)b * HW + m0) * C8_;
    const unsigned short* kb = ko + ((size_t)b * HW + n0) * C8_;

    #pragma unroll
    for (int kt = 0; kt < 2; ++kt) {
        int ko8 = kt * 32 + lq * 8;
        bf16x8 af[3], bfr[3];
        #pragma unroll
        for (int i = 0; i < 3; ++i)
            af[i] = *(const bf16x8*)(qb + (i * 16 + l15) * C8_ + ko8);
        #pragma unroll
        for (int j = 0; j < 3; ++j)
            bfr[j] = *(const bf16x8*)(kb + (j * 16 + l15) * C8_ + ko8);
        #pragma unroll
        for (int i = 0; i < 3; ++i)
            #pragma unroll
            for (int j = 0; j < 3; ++j)
                acc[i][j] = __builtin_amdgcn_mfma_f32_16x16x32_bf16(af[i], bfr[j], acc[i][j], 0, 0, 0);
    }

    __shared__ float red[4][48];
    #pragma unroll
    for (int i = 0; i < 3; ++i) {
        float rm[4];
        #pragma unroll
        for (int r = 0; r < 4; ++r) rm[r] = -1e30f;
        #pragma unroll
        for (int j = 0; j < 3; ++j)
            #pragma unroll
            for (int r = 0; r < 4; ++r)
                rm[r] = fmaxf(rm[r], acc[i][j][r]);
        #pragma unroll
        for (int msk = 1; msk <= 8; msk <<= 1)
            #pragma unroll
            for (int r = 0; r < 4; ++r)
                rm[r] = fmaxf(rm[r], __shfl_xor(rm[r], msk));
        if (l15 == 0) {
            #pragma unroll
            for (int r = 0; r < 4; ++r)
                red[w][i * 16 + lq * 4 + r] = rm[r];
        }
    }
    __syncthreads();
    if (tid < 48) {
        float v = fmaxf(fmaxf(red[0][tid], red[1][tid]),
                        fmaxf(red[2][tid], red[3][tid]));
        out[((size_t)B_ * B_ + b) * HW + m0 + tid] = v;
    }
}

// ---------------- Kernel 5: Gram tiles + fused row/col max (round-3/6) ------
__global__ __launch_bounds__(512) void gram(const unsigned short* __restrict__ xt,
                                            float* __restrict__ out) {
    extern __shared__ char smem[];
    float* colbuf = (float*)(smem + 2 * TILE_B * 2);           // [2][192]
    float* rowbuf = (float*)(smem + 2 * TILE_B * 2 + 1536);    // [4][192]

    int tid = threadIdx.x;
    int bid = (blockIdx.x & 7) * 66 + (blockIdx.x >> 3);       // 528 = 8*66
    int idx = bid, g = 0;
    while (idx >= B_ - g) { idx -= B_ - g; ++g; }
    int p = g + idx;

    const unsigned short* xg = xt + (size_t)g * HW * CC;
    const unsigned short* xp = xt + (size_t)p * HW * CC;

    int w = tid >> 6, lane = tid & 63;
    int wr = w >> 2, wc = w & 3;                // 2 x 4 wave grid
    int l15 = lane & 15, lq = lane >> 4;

    int l8 = lane >> 3, s8 = lane & 7;
    const unsigned short* agp = xg + (size_t)(24 * w + l8) * CC + ((s8 ^ l8) << 3);
    const unsigned short* bgp = xp + (size_t)(24 * w + l8) * CC + ((s8 ^ l8) << 3);
    unsigned ldsw = (unsigned)(24 * w) * 128;

    unsigned aoff[6], boff[3];
    #pragma unroll
    for (int i = 0; i < 6; ++i) {
        int row = wr * 96 + i * 16 + l15;
        aoff[i] = row * 128 + ((unsigned)(lq ^ (row & 7)) << 4);
    }
    #pragma unroll
    for (int j = 0; j < 3; ++j) {
        int row = wc * 48 + j * 16 + l15;
        boff[j] = row * 128 + ((unsigned)(lq ^ (row & 7)) << 4);
    }

    f32x4 acc[6][3];
    #pragma unroll
    for (int i = 0; i < 6; ++i)
        #pragma unroll
        for (int j = 0; j < 3; ++j)
            acc[i][j] = (f32x4){0.f, 0.f, 0.f, 0.f};

    #define STAGE(buf, k0)                                                     \
        {                                                                      \
            char* ab = smem + (buf) * TILE_B + ldsw;                           \
            char* bb = smem + 2 * TILE_B + (buf) * TILE_B + ldsw;              \
            _Pragma("unroll")                                                  \
            for (int ci = 0; ci < 3; ++ci) {                                   \
                gload16(agp + (k0) + ci * 8 * CC, ab + ci * 1024);             \
                gload16(bgp + (k0) + ci * 8 * CC, bb + ci * 1024);             \
            }                                                                  \
        }

    STAGE(0, 0);
    __syncthreads();

    for (int kt = 0; kt < 8; ++kt) {
        int cur = kt & 1;
        if (kt < 7) STAGE(cur ^ 1, (kt + 1) * 64);
        const char* Ab = smem + cur * TILE_B;
        const char* Bb = smem + 2 * TILE_B + cur * TILE_B;
        #pragma unroll
        for (int kx = 0; kx < 128; kx += 64) {   // kk = 0, 32
            bf16x8 af[6], bfr[3];
            #pragma unroll
            for (int i = 0; i < 6; ++i)
                af[i] = *(const bf16x8*)(Ab + (aoff[i] ^ kx));
            #pragma unroll
            for (int j = 0; j < 3; ++j)
                bfr[j] = *(const bf16x8*)(Bb + (boff[j] ^ kx));
            #pragma unroll
            for (int i = 0; i < 6; ++i)
                #pragma unroll
                for (int j = 0; j < 3; ++j)
                    acc[i][j] = __builtin_amdgcn_mfma_f32_16x16x32_bf16(
                        af[i], bfr[j], acc[i][j], 0, 0, 0);
        }
        __syncthreads();
    }

    #pragma unroll
    for (int j = 0; j < 3; ++j) {
        float cm = -1e30f;
        #pragma unroll
        for (int i = 0; i < 6; ++i)
            #pragma unroll
            for (int r = 0; r < 4; ++r)
                cm = fmaxf(cm, acc[i][j][r]);
        cm = fmaxf(cm, __shfl_xor(cm, 16));
        cm = fmaxf(cm, __shfl_xor(cm, 32));
        if (lane < 16) colbuf[wr * HW + wc * 48 + j * 16 + l15] = cm;
    }
    #pragma unroll
    for (int i = 0; i < 6; ++i) {
        float rm[4];
        #pragma unroll
        for (int r = 0; r < 4; ++r) rm[r] = -1e30f;
        #pragma unroll
        for (int j = 0; j < 3; ++j)
            #pragma unroll
            for (int r = 0; r < 4; ++r)
                rm[r] = fmaxf(rm[r], acc[i][j][r]);
        #pragma unroll
        for (int msk = 1; msk <= 8; msk <<= 1)
            #pragma unroll
            for (int r = 0; r < 4; ++r)
                rm[r] = fmaxf(rm[r], __shfl_xor(rm[r], msk));
        if (l15 == 0) {
            #pragma unroll
            for (int r = 0; r < 4; ++r)
                rowbuf[wc * HW + wr * 96 + i * 16 + lq * 4 + r] = rm[r];
        }
    }
    __syncthreads();
    if (tid < HW) {
        float cmax = fmaxf(colbuf[tid], colbuf[HW + tid]);
        out[((size_t)g * B_ + p) * HW + tid] = cmax;
        float rmax = fmaxf(fmaxf(rowbuf[tid], rowbuf[HW + tid]),
                           fmaxf(rowbuf[2 * HW + tid], rowbuf[3 * HW + tid]));
        out[((size_t)p * B_ + g) * HW + tid] = rmax;
    }
}

extern "C" void kernel_launch(void* const* d_in, const int* in_sizes, int n_in,
                              void* d_out, int out_size, void* d_ws, size_t ws_size,
                              hipStream_t stream) {
    (void)in_sizes; (void)n_in; (void)out_size; (void)ws_size;
    const float* x  = (const float*)d_in[0];
    const float* Wq = (const float*)d_in[1];
    const float* bq = (const float*)d_in[2];
    const float* Wk = (const float*)d_in[3];
    const float* bk = (const float*)d_in[4];
    float* out = (float*)d_out;

    char* ws = (char*)d_ws;
    unsigned short* xt  = (unsigned short*)ws;                       // 6291456 B
    unsigned short* wqb = (unsigned short*)(ws + 6291456);           // 65536 B
    unsigned short* wkb = (unsigned short*)(ws + 6291456 + 65536);   // 65536 B
    unsigned short* qbuf = (unsigned short*)(ws + 6291456 + 131072); // 786432 B
    unsigned short* kbuf = (unsigned short*)(ws + 6291456 + 131072 + 786432);

    hipFuncSetAttribute((const void*)gram,
                        hipFuncAttributeMaxDynamicSharedMemorySize, SMEM_BYTES);

    k_transpose<<<dim3(96, 8), dim3(256), 0, stream>>>(x, xt);
    wcvt<<<dim3(64), dim3(256), 0, stream>>>(Wq, Wk, wqb, wkb);
    pam_qk<<<dim3(32, 4), dim3(256), 0, stream>>>(xt, wqb, wkb, bq, bk, qbuf, kbuf);
    pam_energy<<<dim3(32, 4), dim3(256), 0, stream>>>(qbuf, kbuf, out);
    gram<<<dim3(NTRI), dim3(512), SMEM_BYTES, stream>>>(xt, out);
}